// Round 5
// baseline (4781.141 us; speedup 1.0000x reference)
//
#include <hip/hip_runtime.h>
#include <hip/hip_cooperative_groups.h>
#include <math.h>

namespace cg = cooperative_groups;

#define M_SLOTS 8192
#define N_DIM   4096
#define FVS     64
#define PLEN    64
#define CDIM    256
#define NIN     512
#define NOUT    512
#define STEPS   8
#define EPS_F   1e-8f

#define BLK_THR   256
#define MAX_BLKS  1024

#define RCHUNK  16
#define NCHUNKS (M_SLOTS / RCHUNK)      // 512 (fallback path)

struct NtmParams {
    const float *x, *program, *memory0, *in_emb, *out_emb;
    const float *Wc, *bc, *Wk, *bk, *We, *be, *Wa, *ba, *Wrk, *brk;
    float *out;
    float *mem, *partial, *pstat, *X, *c, *k, *e, *a, *kr;
    float *ww, *wr, *red, *wsv, *wse, *n2v;
};

// ---------------- shared helpers ----------------

__device__ inline float wave_sum(float v) {
    for (int off = 32; off; off >>= 1) v += __shfl_down(v, off);
    return v;
}

__device__ inline float blk_sum_256(float v, float* sh) {
    v = wave_sum(v);
    int lane = threadIdx.x & 63, wid = threadIdx.x >> 6;
    if (lane == 0) sh[wid] = v;
    __syncthreads();
    float r = sh[0] + sh[1] + sh[2] + sh[3];
    __syncthreads();
    return r;
}

__device__ inline float blk_max_256(float v, float* sh) {
    for (int off = 32; off; off >>= 1) v = fmaxf(v, __shfl_down(v, off));
    int lane = threadIdx.x & 63, wid = threadIdx.x >> 6;
    if (lane == 0) sh[wid] = v;
    __syncthreads();
    float r = fmaxf(fmaxf(sh[0], sh[1]), fmaxf(sh[2], sh[3]));
    __syncthreads();
    return r;
}

__device__ inline float blk_sum_1024(float v, float* sh) {
    v = wave_sum(v);
    int lane = threadIdx.x & 63, wid = threadIdx.x >> 6;
    if (lane == 0) sh[wid] = v;
    __syncthreads();
    if (threadIdx.x < 16) {
        v = sh[threadIdx.x];
        for (int off = 8; off; off >>= 1) v += __shfl_down(v, off);
        if (threadIdx.x == 0) sh[16] = v;
    }
    __syncthreads();
    float r = sh[16];
    __syncthreads();
    return r;
}

__device__ inline float blk_max_1024(float v, float* sh) {
    for (int off = 32; off; off >>= 1) v = fmaxf(v, __shfl_down(v, off));
    int lane = threadIdx.x & 63, wid = threadIdx.x >> 6;
    if (lane == 0) sh[wid] = v;
    __syncthreads();
    if (threadIdx.x < 16) {
        v = sh[threadIdx.x];
        for (int off = 8; off; off >>= 1) v = fmaxf(v, __shfl_down(v, off));
        if (threadIdx.x == 0) sh[16] = v;
    }
    __syncthreads();
    float r = sh[16];
    __syncthreads();
    return r;
}

// ================= cooperative persistent kernel =================

__global__ __launch_bounds__(BLK_THR, 4) void ntm_mega(NtmParams p) {
    cg::grid_group grid = cg::this_grid();
    const int tid  = threadIdx.x;
    const int bid  = blockIdx.x;
    const int nb   = gridDim.x;
    const int lane = tid & 63;
    const int wid  = tid >> 6;

    __shared__ float shc[4][8];
    __shared__ float gsh[4][64];
    __shared__ float sh4[4];
    __shared__ float in0[FVS + PLEN];
    __shared__ float xs2[FVS];

    // ---------- Phase 0: X = x @ in_emb ; c = sigmoid(Wc [X,prog0] + bc) ----------
    if (bid == 0) {
        if (tid < FVS) {
            float acc = 0.f;
            for (int i = 0; i < NIN; ++i) acc += p.x[i] * p.in_emb[i * FVS + tid];
            p.X[tid] = acc;
            in0[tid] = acc;
        } else if (tid < FVS + PLEN) {
            in0[tid] = p.program[tid - FVS];
        }
        __syncthreads();
        float acc = p.bc[tid];
        const float* wrow = p.Wc + tid * (FVS + PLEN);
        #pragma unroll 8
        for (int i = 0; i < FVS + PLEN; ++i) acc += wrow[i] * in0[i];
        p.c[tid] = 1.f / (1.f + expf(-acc));
    }
    grid.sync();

    for (int t = 0; t < STEPS; ++t) {
        const float* src  = (t == 0) ? p.memory0 : p.mem;
        const float* prog = p.program + t * PLEN;

        // ---------- B: keys (wave-stride over 4096 rows) ----------
        {
            const float4 cv = ((const float4*)p.c)[lane];
            for (int gw = bid * 4 + wid; gw < 4096; gw += nb * 4) {
                float4 wv;
                wv = ((const float4*)(p.Wk + (size_t)gw * CDIM))[lane];
                float sK = wv.x*cv.x + wv.y*cv.y + wv.z*cv.z + wv.w*cv.w;
                wv = ((const float4*)(p.We + (size_t)gw * CDIM))[lane];
                float sE = wv.x*cv.x + wv.y*cv.y + wv.z*cv.z + wv.w*cv.w;
                wv = ((const float4*)(p.Wa + (size_t)gw * CDIM))[lane];
                float sA = wv.x*cv.x + wv.y*cv.y + wv.z*cv.z + wv.w*cv.w;
                float sR = p.Wrk[(size_t)gw * PLEN + lane] * prog[lane];
                sK = wave_sum(sK); sE = wave_sum(sE); sA = wave_sum(sA); sR = wave_sum(sR);
                if (lane == 0) {
                    p.k[gw]  = tanhf(sK + p.bk[gw]);
                    p.e[gw]  = 1.f / (1.f + expf(-(sE + p.be[gw])));
                    p.a[gw]  = tanhf(sA + p.ba[gw]);
                    p.kr[gw] = tanhf(sR + p.brk[gw]);
                }
            }
        }
        grid.sync();

        // ---------- C: 8 row-stats, 1024 chunks (colsplit x2, 16 rows) ----------
        for (int ch = bid; ch < 1024; ch += nb) {
            const int cs = ch & 1;
            const int rc = ch >> 1;                  // [0, 512)
            const int i0 = cs * 512 + tid;           // float4 col index
            const int i1 = i0 + 256;
            const float4 K0 = ((const float4*)p.k )[i0], K1 = ((const float4*)p.k )[i1];
            const float4 R0 = ((const float4*)p.kr)[i0], R1 = ((const float4*)p.kr)[i1];
            const float4 A0 = ((const float4*)p.a )[i0], A1 = ((const float4*)p.a )[i1];
            const float4 E0 = ((const float4*)p.e )[i0], E1 = ((const float4*)p.e )[i1];
            for (int r = 0; r < 16; ++r) {
                const int m = rc * 16 + r;
                const float4* row = (const float4*)(src + (size_t)m * N_DIM);
                float4 v0 = row[i0], v1 = row[i1];
                float s0=0,s1=0,s2=0,s3=0,s4=0,s5=0,s6=0,s7=0;
                #define ACC1(vv,kk,rr2,aaa,eee) { float _v=vv,_k=kk,_r=rr2,_a=aaa,_e=eee; \
                    float _ve=_v*_e, _v2=_v*_v, _v2e=_v2*_e; \
                    s0+=_v*_k; s1+=_v*_r; s2+=_ve*_r; s3+=_v*_a; s4+=_ve*_a; \
                    s5+=_v2; s6+=_v2e; s7+=_v2e*_e; }
                ACC1(v0.x,K0.x,R0.x,A0.x,E0.x) ACC1(v0.y,K0.y,R0.y,A0.y,E0.y)
                ACC1(v0.z,K0.z,R0.z,A0.z,E0.z) ACC1(v0.w,K0.w,R0.w,A0.w,E0.w)
                ACC1(v1.x,K1.x,R1.x,A1.x,E1.x) ACC1(v1.y,K1.y,R1.y,A1.y,E1.y)
                ACC1(v1.z,K1.z,R1.z,A1.z,E1.z) ACC1(v1.w,K1.w,R1.w,A1.w,E1.w)
                #undef ACC1
                s0 = wave_sum(s0); s1 = wave_sum(s1); s2 = wave_sum(s2); s3 = wave_sum(s3);
                s4 = wave_sum(s4); s5 = wave_sum(s5); s6 = wave_sum(s6); s7 = wave_sum(s7);
                if (lane == 0) {
                    shc[wid][0]=s0; shc[wid][1]=s1; shc[wid][2]=s2; shc[wid][3]=s3;
                    shc[wid][4]=s4; shc[wid][5]=s5; shc[wid][6]=s6; shc[wid][7]=s7;
                }
                __syncthreads();
                if (tid < 8) {
                    float tot = shc[0][tid]+shc[1][tid]+shc[2][tid]+shc[3][tid];
                    p.pstat[(size_t)(tid*2+cs) * M_SLOTS + m] = tot;
                }
                __syncthreads();
            }
        }
        grid.sync();

        // ---------- DE: block 0 computes both softmaxes ----------
        if (bid == 0) {
            float a0=0,a1=0,a2=0,a3=0;
            for (int i = tid; i < N_DIM; i += BLK_THR) {
                float kv=p.k[i], rv=p.kr[i], av=p.a[i];
                a0+=kv*kv; a1+=rv*rv; a2+=av*rv; a3+=av*av;
            }
            float d0 = blk_sum_256(a0, sh4);
            float d1 = blk_sum_256(a1, sh4);
            float d2 = blk_sum_256(a2, sh4);
            float d3 = blk_sum_256(a3, sh4);
            float knorm = sqrtf(d0), krnorm = sqrtf(d1);

            float mx = -INFINITY;
            for (int j = 0; j < M_SLOTS / BLK_THR; ++j) {
                int m = tid + j * BLK_THR;
                float sim = p.pstat[(size_t)0*M_SLOTS+m] + p.pstat[(size_t)1*M_SLOTS+m];
                float n2  = p.pstat[(size_t)10*M_SLOTS+m] + p.pstat[(size_t)11*M_SLOTS+m];
                float v = sim / (sqrtf(n2) * knorm + EPS_F);
                p.wsv[m] = v; p.n2v[m] = n2;
                mx = fmaxf(mx, v);
            }
            mx = blk_max_256(mx, sh4);
            float ls = 0.f;
            for (int j = 0; j < M_SLOTS / BLK_THR; ++j) {
                int m = tid + j * BLK_THR;
                float evv = expf(p.wsv[m] - mx);
                p.wse[m] = evv; ls += evv;
            }
            ls = blk_sum_256(ls, sh4);
            float inv = 1.f / ls;
            for (int j = 0; j < M_SLOTS / BLK_THR; ++j) {
                int m = tid + j * BLK_THR;
                p.ww[m] = p.wse[m] * inv;
            }
            float mx2 = -INFINITY;
            for (int j = 0; j < M_SLOTS / BLK_THR; ++j) {
                int m = tid + j * BLK_THR;
                float w1 = p.wse[m] * inv;
                float skr  = p.pstat[(size_t)2*M_SLOTS+m]  + p.pstat[(size_t)3*M_SLOTS+m];
                float sekr = p.pstat[(size_t)4*M_SLOTS+m]  + p.pstat[(size_t)5*M_SLOTS+m];
                float sa_  = p.pstat[(size_t)6*M_SLOTS+m]  + p.pstat[(size_t)7*M_SLOTS+m];
                float sea_ = p.pstat[(size_t)8*M_SLOTS+m]  + p.pstat[(size_t)9*M_SLOTS+m];
                float qe_  = p.pstat[(size_t)12*M_SLOTS+m] + p.pstat[(size_t)13*M_SLOTS+m];
                float qe2_ = p.pstat[(size_t)14*M_SLOTS+m] + p.pstat[(size_t)15*M_SLOTS+m];
                float sim2 = skr - w1 * sekr + w1 * d2;
                float n2n  = p.n2v[m] - 2.f*w1*qe_ + w1*w1*qe2_
                           + 2.f*w1*sa_ - 2.f*w1*w1*sea_ + w1*w1*d3;
                float v = sim2 / (sqrtf(n2n) * krnorm + EPS_F);
                p.wsv[m] = v;
                mx2 = fmaxf(mx2, v);
            }
            mx2 = blk_max_256(mx2, sh4);
            float ls2 = 0.f;
            for (int j = 0; j < M_SLOTS / BLK_THR; ++j) {
                int m = tid + j * BLK_THR;
                float evv = expf(p.wsv[m] - mx2);
                p.wse[m] = evv; ls2 += evv;
            }
            ls2 = blk_sum_256(ls2, sh4);
            float inv2 = 1.f / ls2;
            for (int j = 0; j < M_SLOTS / BLK_THR; ++j) {
                int m = tid + j * BLK_THR;
                p.wr[m] = p.wse[m] * inv2;
            }
        }
        grid.sync();

        // ---------- F: mem update + fused read partials (1024 chunks) ----------
        for (int ch = bid; ch < 1024; ch += nb) {
            const int cs  = ch & 3;
            const int rc  = ch >> 2;              // [0, 256), 32 rows each
            const int c4i = cs * 256 + tid;       // [0, 1024) float4 cols
            const float4 ee = ((const float4*)p.e)[c4i];
            const float4 aa = ((const float4*)p.a)[c4i];
            float4 acc = make_float4(0.f, 0.f, 0.f, 0.f);
            const float4* s4 = (const float4*)src;
            float4* d4 = (float4*)p.mem;
            for (int r = 0; r < 32; ++r) {
                const int m = rc * 32 + r;
                float w1 = p.ww[m], w2 = p.wr[m];
                float4 v = s4[(size_t)m * (N_DIM/4) + c4i];
                float4 nv;
                nv.x = v.x * (1.f - w1 * ee.x) + w1 * aa.x;
                nv.y = v.y * (1.f - w1 * ee.y) + w1 * aa.y;
                nv.z = v.z * (1.f - w1 * ee.z) + w1 * aa.z;
                nv.w = v.w * (1.f - w1 * ee.w) + w1 * aa.w;
                d4[(size_t)m * (N_DIM/4) + c4i] = nv;
                acc.x += w2 * nv.x; acc.y += w2 * nv.y;
                acc.z += w2 * nv.z; acc.w += w2 * nv.w;
            }
            ((float4*)p.partial)[(size_t)rc * (N_DIM/4) + c4i] = acc;
        }
        grid.sync();

        // ---------- G: reduce partial[256][N_DIM] -> red (64 chunks) ----------
        for (int j = bid; j < 64; j += nb) {
            const int col = j * 64 + lane;
            float acc = 0.f;
            for (int r = wid * 64; r < wid * 64 + 64; ++r)
                acc += p.partial[(size_t)r * N_DIM + col];
            gsh[wid][lane] = acc;
            __syncthreads();
            if (tid < 64)
                p.red[j * 64 + tid] = gsh[0][tid] + gsh[1][tid] + gsh[2][tid] + gsh[3][tid];
            __syncthreads();
        }
        grid.sync();

        // ---------- H: X = tanh(X @ red); next c or output ----------
        if (bid == 0) {
            if (tid < FVS) xs2[tid] = p.X[tid];
            __syncthreads();
            float xn = 0.f;
            if (tid < FVS) {
                float acc = 0.f;
                #pragma unroll
                for (int i = 0; i < FVS; ++i) acc += xs2[i] * p.red[i * FVS + tid];
                xn = tanhf(acc);
                p.X[tid] = xn;
            }
            __syncthreads();
            if (tid < FVS) xs2[tid] = xn;
            __syncthreads();
            if (t < STEPS - 1) {
                const float* pn = p.program + (t + 1) * PLEN;
                float acc = p.bc[tid];
                const float* wrow = p.Wc + tid * (FVS + PLEN);
                #pragma unroll
                for (int i = 0; i < FVS; ++i) acc += wrow[i] * xs2[i];
                #pragma unroll
                for (int i = 0; i < PLEN; ++i) acc += wrow[FVS + i] * pn[i];
                p.c[tid] = 1.f / (1.f + expf(-acc));
            } else {
                for (int col = tid; col < NOUT; col += BLK_THR) {
                    float acc = 0.f;
                    #pragma unroll
                    for (int i = 0; i < FVS; ++i) acc += xs2[i] * p.out_emb[i * NOUT + col];
                    p.out[col] = acc;
                }
            }
        }
        grid.sync();
    }
}

// ================= fallback multi-kernel path (round-3, validated) =================

__global__ void k_init_ctrl(const float* __restrict__ x, const float* __restrict__ emb,
                            const float* __restrict__ prog0,
                            const float* __restrict__ Wc, const float* __restrict__ bc,
                            float* __restrict__ X, float* __restrict__ c) {
    __shared__ float in[FVS + PLEN];
    int tid = threadIdx.x;  // 256
    if (tid < FVS) {
        float acc = 0.f;
        for (int i = 0; i < NIN; ++i) acc += x[i] * emb[i * FVS + tid];
        X[tid] = acc;
        in[tid] = acc;
    } else if (tid < FVS + PLEN) {
        in[tid] = prog0[tid - FVS];
    }
    __syncthreads();
    float acc = bc[tid];
    const float* wrow = Wc + tid * (FVS + PLEN);
    #pragma unroll 8
    for (int i = 0; i < FVS + PLEN; ++i) acc += wrow[i] * in[i];
    c[tid] = 1.f / (1.f + expf(-acc));
}

__global__ void k_keys(const float* __restrict__ c, const float* __restrict__ prog_t,
                       const float* __restrict__ Wk, const float* __restrict__ bk,
                       const float* __restrict__ We, const float* __restrict__ be,
                       const float* __restrict__ Wa, const float* __restrict__ ba,
                       const float* __restrict__ Wrk, const float* __restrict__ brk,
                       float* __restrict__ k, float* __restrict__ e,
                       float* __restrict__ a, float* __restrict__ kr) {
    int gw   = (blockIdx.x * blockDim.x + threadIdx.x) >> 6;
    int lane = threadIdx.x & 63;
    int mat  = gw >> 12;
    int row  = gw & 4095;
    float acc = 0.f;
    if (mat == 0) {
        const float* W = Wk + row * CDIM;
        #pragma unroll
        for (int i = lane; i < CDIM; i += 64) acc += W[i] * c[i];
    } else if (mat == 1) {
        const float* W = We + row * CDIM;
        #pragma unroll
        for (int i = lane; i < CDIM; i += 64) acc += W[i] * c[i];
    } else if (mat == 2) {
        const float* W = Wa + row * CDIM;
        #pragma unroll
        for (int i = lane; i < CDIM; i += 64) acc += W[i] * c[i];
    } else {
        acc = Wrk[row * PLEN + lane] * prog_t[lane];
    }
    acc = wave_sum(acc);
    if (lane == 0) {
        if (mat == 0)      k[row]  = tanhf(acc + bk[row]);
        else if (mat == 1) e[row]  = 1.f / (1.f + expf(-(acc + be[row])));
        else if (mat == 2) a[row]  = tanhf(acc + ba[row]);
        else               kr[row] = tanhf(acc + brk[row]);
    }
}

__global__ __launch_bounds__(256) void k_sim8(
        const float* __restrict__ mem,
        const float* __restrict__ k, const float* __restrict__ kr,
        const float* __restrict__ a, const float* __restrict__ e,
        float* __restrict__ simk, float* __restrict__ n2old,
        float* __restrict__ skr, float* __restrict__ sekr,
        float* __restrict__ sa, float* __restrict__ sea,
        float* __restrict__ qe, float* __restrict__ qe2) {
    int m = blockIdx.x;
    int tid = threadIdx.x;
    const float4* row = (const float4*)(mem + (size_t)m * N_DIM);
    const float4* K4  = (const float4*)k;
    const float4* R4  = (const float4*)kr;
    const float4* A4  = (const float4*)a;
    const float4* E4  = (const float4*)e;
    float s0=0,s1=0,s2=0,s3=0,s4=0,s5=0,s6=0,s7=0;
    #pragma unroll
    for (int ii = 0; ii < N_DIM / 4 / 256; ++ii) {
        int i = tid + ii * 256;
        float4 v  = row[i];
        float4 kk = K4[i];
        float4 rr = R4[i];
        float4 aa = A4[i];
        float4 ee = E4[i];
        #define ACC1(c) { float vv=v.c, kv=kk.c, rv=rr.c, av=aa.c, ev=ee.c; \
            float ve = vv*ev; float v2 = vv*vv; \
            s0 += vv*kv; s1 += vv*rv; s2 += ve*rv; s3 += vv*av; s4 += ve*av; \
            s5 += v2; s6 += v2*ev; s7 += v2*(ev*ev); }
        ACC1(x) ACC1(y) ACC1(z) ACC1(w)
        #undef ACC1
    }
    s0 = wave_sum(s0); s1 = wave_sum(s1); s2 = wave_sum(s2); s3 = wave_sum(s3);
    s4 = wave_sum(s4); s5 = wave_sum(s5); s6 = wave_sum(s6); s7 = wave_sum(s7);
    __shared__ float sh[4][8];
    int lane = tid & 63, wid = tid >> 6;
    if (lane == 0) {
        sh[wid][0]=s0; sh[wid][1]=s1; sh[wid][2]=s2; sh[wid][3]=s3;
        sh[wid][4]=s4; sh[wid][5]=s5; sh[wid][6]=s6; sh[wid][7]=s7;
    }
    __syncthreads();
    if (tid < 8) {
        float tot = sh[0][tid] + sh[1][tid] + sh[2][tid] + sh[3][tid];
        switch (tid) {
            case 0: simk[m]  = tot; break;
            case 1: skr[m]   = tot; break;
            case 2: sekr[m]  = tot; break;
            case 3: sa[m]    = tot; break;
            case 4: sea[m]   = tot; break;
            case 5: n2old[m] = tot; break;
            case 6: qe[m]    = tot; break;
            case 7: qe2[m]   = tot; break;
        }
    }
}

__global__ __launch_bounds__(1024) void k_addr(
        const float* __restrict__ k, const float* __restrict__ kr, const float* __restrict__ a,
        const float* __restrict__ simk, const float* __restrict__ n2old,
        const float* __restrict__ skr, const float* __restrict__ sekr,
        const float* __restrict__ sa, const float* __restrict__ sea,
        const float* __restrict__ qe, const float* __restrict__ qe2,
        float* __restrict__ ww, float* __restrict__ wr) {
    __shared__ float sh[17];
    int tid = threadIdx.x;
    float d0=0,d1=0,d2=0,d3=0;
    for (int i = tid; i < N_DIM; i += 1024) {
        float kv = k[i], krv = kr[i], av = a[i];
        d0 += kv*kv; d1 += krv*krv; d2 += av*krv; d3 += av*av;
    }
    d0 = blk_sum_1024(d0, sh);
    d1 = blk_sum_1024(d1, sh);
    d2 = blk_sum_1024(d2, sh);
    d3 = blk_sum_1024(d3, sh);
    float knorm = sqrtf(d0), krnorm = sqrtf(d1);

    float v[M_SLOTS / 1024];
    float mx = -INFINITY;
    #pragma unroll
    for (int j = 0; j < M_SLOTS / 1024; ++j) {
        int m = tid + j * 1024;
        v[j] = simk[m] / (sqrtf(n2old[m]) * knorm + EPS_F);
        mx = fmaxf(mx, v[j]);
    }
    mx = blk_max_1024(mx, sh);
    float ls = 0.f;
    #pragma unroll
    for (int j = 0; j < M_SLOTS / 1024; ++j) { v[j] = expf(v[j] - mx); ls += v[j]; }
    ls = blk_sum_1024(ls, sh);
    float inv = 1.f / ls;
    float wv[M_SLOTS / 1024];
    #pragma unroll
    for (int j = 0; j < M_SLOTS / 1024; ++j) {
        wv[j] = v[j] * inv;
        ww[tid + j * 1024] = wv[j];
    }

    float mx2 = -INFINITY;
    #pragma unroll
    for (int j = 0; j < M_SLOTS / 1024; ++j) {
        int m = tid + j * 1024;
        float w1 = wv[j];
        float sim2 = skr[m] - w1 * sekr[m] + w1 * d2;
        float n2 = n2old[m] - 2.f*w1*qe[m] + w1*w1*qe2[m]
                 + 2.f*w1*sa[m] - 2.f*w1*w1*sea[m] + w1*w1*d3;
        v[j] = sim2 / (sqrtf(n2) * krnorm + EPS_F);
        mx2 = fmaxf(mx2, v[j]);
    }
    mx2 = blk_max_1024(mx2, sh);
    float ls2 = 0.f;
    #pragma unroll
    for (int j = 0; j < M_SLOTS / 1024; ++j) { v[j] = expf(v[j] - mx2); ls2 += v[j]; }
    ls2 = blk_sum_1024(ls2, sh);
    float inv2 = 1.f / ls2;
    #pragma unroll
    for (int j = 0; j < M_SLOTS / 1024; ++j) wr[tid + j * 1024] = v[j] * inv2;
}

__global__ void k_update_read(const float* __restrict__ src, float* __restrict__ dst,
                              const float* __restrict__ ww, const float* __restrict__ wr,
                              const float* __restrict__ e, const float* __restrict__ a,
                              float* __restrict__ partial) {
    int c4 = blockIdx.x * 256 + threadIdx.x;   // [0, 1024)
    int rc = blockIdx.y;                       // [0, NCHUNKS)
    int r0 = rc * RCHUNK;
    const float4* s4 = (const float4*)src;
    float4*       d4 = (float4*)dst;
    float4 ee = ((const float4*)e)[c4];
    float4 aa = ((const float4*)a)[c4];
    float4 acc = make_float4(0.f, 0.f, 0.f, 0.f);
    #pragma unroll
    for (int r = r0; r < r0 + RCHUNK; ++r) {
        float w1 = ww[r], w2 = wr[r];
        float4 v = s4[(size_t)r * (N_DIM / 4) + c4];
        float4 nv;
        nv.x = v.x * (1.f - w1 * ee.x) + w1 * aa.x;
        nv.y = v.y * (1.f - w1 * ee.y) + w1 * aa.y;
        nv.z = v.z * (1.f - w1 * ee.z) + w1 * aa.z;
        nv.w = v.w * (1.f - w1 * ee.w) + w1 * aa.w;
        d4[(size_t)r * (N_DIM / 4) + c4] = nv;
        acc.x += w2 * nv.x; acc.y += w2 * nv.y; acc.z += w2 * nv.z; acc.w += w2 * nv.w;
    }
    ((float4*)partial)[(size_t)rc * (N_DIM / 4) + c4] = acc;
}

__global__ void k_read_reduce(const float* __restrict__ partial, float* __restrict__ red) {
    int cidx = blockIdx.x * 256 + threadIdx.x;
    float acc = 0.f;
    #pragma unroll 8
    for (int j = 0; j < NCHUNKS; ++j) acc += partial[(size_t)j * N_DIM + cidx];
    red[cidx] = acc;
}

__global__ void k_exec_ctrl(float* __restrict__ X, const float* __restrict__ red,
                            const float* __restrict__ prog_next,
                            const float* __restrict__ Wc, const float* __restrict__ bc,
                            float* __restrict__ c, int do_ctrl) {
    __shared__ float in[FVS + PLEN];
    __shared__ float xs[FVS];
    int tid = threadIdx.x;  // 256
    if (tid < FVS) xs[tid] = X[tid];
    __syncthreads();
    if (tid < FVS) {
        float acc = 0.f;
        #pragma unroll
        for (int i = 0; i < FVS; ++i) acc += xs[i] * red[i * FVS + tid];
        float xn = tanhf(acc);
        X[tid] = xn;
        in[tid] = xn;
    } else if (do_ctrl && tid < FVS + PLEN) {
        in[tid] = prog_next[tid - FVS];
    }
    __syncthreads();
    if (do_ctrl) {
        float acc = bc[tid];
        const float* wrow = Wc + tid * (FVS + PLEN);
        #pragma unroll 8
        for (int i = 0; i < FVS + PLEN; ++i) acc += wrow[i] * in[i];
        c[tid] = 1.f / (1.f + expf(-acc));
    }
}

__global__ void k_out(const float* __restrict__ X, const float* __restrict__ emb,
                      float* __restrict__ out) {
    __shared__ float xs[FVS];
    int tid = threadIdx.x;  // 512
    if (tid < FVS) xs[tid] = X[tid];
    __syncthreads();
    float acc = 0.f;
    #pragma unroll
    for (int i = 0; i < FVS; ++i) acc += xs[i] * emb[i * NOUT + tid];
    out[tid] = acc;
}

// ---------------- launch ----------------

extern "C" void kernel_launch(void* const* d_in, const int* in_sizes, int n_in,
                              void* d_out, int out_size, void* d_ws, size_t ws_size,
                              hipStream_t stream) {
    NtmParams p;
    p.x        = (const float*)d_in[0];
    p.program  = (const float*)d_in[1];
    p.memory0  = (const float*)d_in[2];
    p.in_emb   = (const float*)d_in[3];
    p.out_emb  = (const float*)d_in[4];
    p.Wc       = (const float*)d_in[5];
    p.bc       = (const float*)d_in[6];
    p.Wk       = (const float*)d_in[7];
    p.bk       = (const float*)d_in[8];
    p.We       = (const float*)d_in[9];
    p.be       = (const float*)d_in[10];
    p.Wa       = (const float*)d_in[11];
    p.ba       = (const float*)d_in[12];
    p.Wrk      = (const float*)d_in[13];
    p.brk      = (const float*)d_in[14];
    p.out      = (float*)d_out;

    float* ws = (float*)d_ws;
    size_t off = 0;
    p.mem     = ws + off; off += (size_t)M_SLOTS * N_DIM;
    p.partial = ws + off; off += (size_t)NCHUNKS * N_DIM;   // 512 rows (fallback); coop uses 256
    p.pstat   = ws + off; off += (size_t)16 * M_SLOTS;
    p.X       = ws + off; off += FVS;
    p.c       = ws + off; off += CDIM;
    p.k       = ws + off; off += N_DIM;
    p.e       = ws + off; off += N_DIM;
    p.a       = ws + off; off += N_DIM;
    p.kr      = ws + off; off += N_DIM;
    p.ww      = ws + off; off += M_SLOTS;
    p.wr      = ws + off; off += M_SLOTS;
    p.red     = ws + off; off += N_DIM;
    p.wsv     = ws + off; off += M_SLOTS;
    p.wse     = ws + off; off += M_SLOTS;
    p.n2v     = ws + off; off += M_SLOTS;
    // fallback stat arrays
    float* simk  = ws + off; off += M_SLOTS;
    float* n2old = ws + off; off += M_SLOTS;
    float* skr   = ws + off; off += M_SLOTS;
    float* sekr  = ws + off; off += M_SLOTS;
    float* sa    = ws + off; off += M_SLOTS;
    float* sea   = ws + off; off += M_SLOTS;
    float* qe    = ws + off; off += M_SLOTS;
    float* qe2   = ws + off; off += M_SLOTS;

    (void)hipGetLastError();  // clear any stale error

    // Size the cooperative grid from the runtime's occupancy answer.
    int dev = 0;
    (void)hipGetDevice(&dev);
    int cus = 0;
    (void)hipDeviceGetAttribute(&cus, hipDeviceAttributeMultiprocessorCount, dev);
    int occ = 0;
    hipError_t oe = hipOccupancyMaxActiveBlocksPerMultiprocessor(&occ, ntm_mega, BLK_THR, 0);

    bool done = false;
    if (oe == hipSuccess && occ > 0 && cus > 0) {
        long cap = (long)occ * (long)cus;
        int nb = (int)(cap < MAX_BLKS ? cap : MAX_BLKS);
        if (nb >= 256) {
            void* args[] = { &p };
            hipError_t le = hipLaunchCooperativeKernel(
                reinterpret_cast<void*>(ntm_mega), dim3(nb), dim3(BLK_THR), args, 0, stream);
            if (le == hipSuccess) done = true;
            else (void)hipGetLastError();   // clear the failed-launch error
        }
    }

    if (!done) {
        // ---- validated round-3 multi-kernel path ----
        k_init_ctrl<<<1, 256, 0, stream>>>(p.x, p.in_emb, p.program, p.Wc, p.bc, p.X, p.c);
        for (int t = 0; t < STEPS; ++t) {
            const float* prog_t = p.program + t * PLEN;
            const float* src    = (t == 0) ? p.memory0 : p.mem;
            k_keys<<<4096, 256, 0, stream>>>(p.c, prog_t, p.Wk, p.bk, p.We, p.be,
                                             p.Wa, p.ba, p.Wrk, p.brk,
                                             p.k, p.e, p.a, p.kr);
            k_sim8<<<M_SLOTS, 256, 0, stream>>>(
                src, p.k, p.kr, p.a, p.e, simk, n2old, skr, sekr, sa, sea, qe, qe2);
            k_addr<<<1, 1024, 0, stream>>>(p.k, p.kr, p.a, simk, n2old, skr, sekr,
                                           sa, sea, qe, qe2, p.ww, p.wr);
            k_update_read<<<dim3(4, NCHUNKS), 256, 0, stream>>>(
                src, p.mem, p.ww, p.wr, p.e, p.a, p.partial);
            k_read_reduce<<<16, 256, 0, stream>>>(p.partial, p.red);
            k_exec_ctrl<<<1, 256, 0, stream>>>(p.X, p.red,
                (t < STEPS - 1) ? p.program + (t + 1) * PLEN : nullptr,
                p.Wc, p.bc, p.c, (t < STEPS - 1) ? 1 : 0);
        }
        k_out<<<1, NOUT, 0, stream>>>(p.X, p.out_emb, p.out);
    }
}

// Round 6
// 863.874 us; speedup vs baseline: 5.5345x; 5.5345x over previous
//
#include <hip/hip_runtime.h>
#include <math.h>

#define M_SLOTS 8192
#define N_DIM   4096
#define FVS     64
#define PLEN    64
#define CDIM    256
#define NIN     512
#define NOUT    512
#define STEPS   8
#define EPS_F   1e-8f

#define RCHUNK  16
#define NCHUNKS (M_SLOTS / RCHUNK)      // 512

// ---------------- helpers ----------------

__device__ inline float wave_sum(float v) {
    for (int off = 32; off; off >>= 1) v += __shfl_down(v, off);
    return v;
}

__device__ inline float blk_sum_1024(float v, float* sh) {
    v = wave_sum(v);
    int lane = threadIdx.x & 63, wid = threadIdx.x >> 6;
    if (lane == 0) sh[wid] = v;
    __syncthreads();
    if (threadIdx.x < 16) {
        v = sh[threadIdx.x];
        for (int off = 8; off; off >>= 1) v += __shfl_down(v, off);
        if (threadIdx.x == 0) sh[16] = v;
    }
    __syncthreads();
    float r = sh[16];
    __syncthreads();
    return r;
}

// ---------------- kernels ----------------

// X = x @ input_embedding, then c = sigmoid(Wc @ concat(X, prog0) + bc)
__global__ void k_init_ctrl(const float* __restrict__ x, const float* __restrict__ emb,
                            const float* __restrict__ prog0,
                            const float* __restrict__ Wc, const float* __restrict__ bc,
                            float* __restrict__ X, float* __restrict__ c) {
    __shared__ float in[FVS + PLEN];
    int tid = threadIdx.x;  // 256
    if (tid < FVS) {
        float acc = 0.f;
        for (int i = 0; i < NIN; ++i) acc += x[i] * emb[i * FVS + tid];
        X[tid] = acc;
        in[tid] = acc;
    } else if (tid < FVS + PLEN) {
        in[tid] = prog0[tid - FVS];
    }
    __syncthreads();
    float acc = bc[tid];
    const float* wrow = Wc + tid * (FVS + PLEN);
    #pragma unroll 8
    for (int i = 0; i < FVS + PLEN; ++i) acc += wrow[i] * in[i];
    c[tid] = 1.f / (1.f + expf(-acc));
}

// one wave -> key rows (all four outputs), cv = controller as float4 per lane
__device__ inline void keys_row(int gw, float4 cv, int lane, const float* __restrict__ prog,
                                const float* __restrict__ Wk, const float* __restrict__ bk,
                                const float* __restrict__ We, const float* __restrict__ be,
                                const float* __restrict__ Wa, const float* __restrict__ ba,
                                const float* __restrict__ Wrk, const float* __restrict__ brk,
                                float* __restrict__ k, float* __restrict__ e,
                                float* __restrict__ a, float* __restrict__ kr) {
    float4 wv;
    wv = ((const float4*)(Wk + (size_t)gw * CDIM))[lane];
    float sK = wv.x*cv.x + wv.y*cv.y + wv.z*cv.z + wv.w*cv.w;
    wv = ((const float4*)(We + (size_t)gw * CDIM))[lane];
    float sE = wv.x*cv.x + wv.y*cv.y + wv.z*cv.z + wv.w*cv.w;
    wv = ((const float4*)(Wa + (size_t)gw * CDIM))[lane];
    float sA = wv.x*cv.x + wv.y*cv.y + wv.z*cv.z + wv.w*cv.w;
    float sR = Wrk[(size_t)gw * PLEN + lane] * prog[lane];
    sK = wave_sum(sK); sE = wave_sum(sE); sA = wave_sum(sA); sR = wave_sum(sR);
    if (lane == 0) {
        k[gw]  = tanhf(sK + bk[gw]);
        e[gw]  = 1.f / (1.f + expf(-(sE + be[gw])));
        a[gw]  = tanhf(sA + ba[gw]);
        kr[gw] = tanhf(sR + brk[gw]);
    }
}

// standalone keys (step 0): reads global c.  grid 512 x 256 (2048 waves, 2 rows each)
__global__ __launch_bounds__(256) void k_keys4(
        const float* __restrict__ c, const float* __restrict__ prog,
        const float* __restrict__ Wk, const float* __restrict__ bk,
        const float* __restrict__ We, const float* __restrict__ be,
        const float* __restrict__ Wa, const float* __restrict__ ba,
        const float* __restrict__ Wrk, const float* __restrict__ brk,
        float* __restrict__ k, float* __restrict__ e,
        float* __restrict__ a, float* __restrict__ kr) {
    int lane = threadIdx.x & 63, wid = threadIdx.x >> 6;
    const float4 cv = ((const float4*)c)[lane];
    for (int gw = blockIdx.x * 4 + wid; gw < 4096; gw += 2048)
        keys_row(gw, cv, lane, prog, Wk, bk, We, be, Wa, ba, Wrk, brk, k, e, a, kr);
}

// 8 row-reductions over mem, 2 rows per block (m, m+4096).  grid 4096 x 256.
// stat rows: 0 mem.k  1 mem.kr  2 mem.(e*kr)  3 mem.a  4 mem.(e*a)
//            5 |mem|^2  6 mem^2.e  7 mem^2.e^2
__global__ __launch_bounds__(256) void k_sim8(
        const float* __restrict__ mem,
        const float* __restrict__ k, const float* __restrict__ kr,
        const float* __restrict__ a, const float* __restrict__ e,
        float* __restrict__ stat) {
    const int m0 = blockIdx.x, m1 = blockIdx.x + 4096;
    const int tid = threadIdx.x;
    const float4* r0 = (const float4*)(mem + (size_t)m0 * N_DIM);
    const float4* r1 = (const float4*)(mem + (size_t)m1 * N_DIM);
    const float4* K4 = (const float4*)k;
    const float4* R4 = (const float4*)kr;
    const float4* A4 = (const float4*)a;
    const float4* E4 = (const float4*)e;
    float s0=0,s1=0,s2=0,s3=0,s4=0,s5=0,s6=0,s7=0;
    float u0=0,u1=0,u2=0,u3=0,u4=0,u5=0,u6=0,u7=0;
    #pragma unroll
    for (int ii = 0; ii < 4; ++ii) {
        int i = tid + ii * 256;
        float4 kk = K4[i];
        float4 rr = R4[i];
        float4 aa = A4[i];
        float4 ee = E4[i];
        float4 v0 = r0[i];
        float4 v1 = r1[i];
        #define ACC1(S0,S1,S2,S3,S4,S5,S6,S7,vv,kc,rc,ac,ec) { \
            float _v=vv,_k=kc,_r=rc,_a=ac,_e=ec; \
            float _ve=_v*_e, _v2=_v*_v, _v2e=_v2*_e; \
            S0+=_v*_k; S1+=_v*_r; S2+=_ve*_r; S3+=_v*_a; S4+=_ve*_a; \
            S5+=_v2; S6+=_v2e; S7+=_v2e*_e; }
        ACC1(s0,s1,s2,s3,s4,s5,s6,s7, v0.x, kk.x, rr.x, aa.x, ee.x)
        ACC1(s0,s1,s2,s3,s4,s5,s6,s7, v0.y, kk.y, rr.y, aa.y, ee.y)
        ACC1(s0,s1,s2,s3,s4,s5,s6,s7, v0.z, kk.z, rr.z, aa.z, ee.z)
        ACC1(s0,s1,s2,s3,s4,s5,s6,s7, v0.w, kk.w, rr.w, aa.w, ee.w)
        ACC1(u0,u1,u2,u3,u4,u5,u6,u7, v1.x, kk.x, rr.x, aa.x, ee.x)
        ACC1(u0,u1,u2,u3,u4,u5,u6,u7, v1.y, kk.y, rr.y, aa.y, ee.y)
        ACC1(u0,u1,u2,u3,u4,u5,u6,u7, v1.z, kk.z, rr.z, aa.z, ee.z)
        ACC1(u0,u1,u2,u3,u4,u5,u6,u7, v1.w, kk.w, rr.w, aa.w, ee.w)
        #undef ACC1
    }
    s0=wave_sum(s0); s1=wave_sum(s1); s2=wave_sum(s2); s3=wave_sum(s3);
    s4=wave_sum(s4); s5=wave_sum(s5); s6=wave_sum(s6); s7=wave_sum(s7);
    u0=wave_sum(u0); u1=wave_sum(u1); u2=wave_sum(u2); u3=wave_sum(u3);
    u4=wave_sum(u4); u5=wave_sum(u5); u6=wave_sum(u6); u7=wave_sum(u7);
    __shared__ float shc[4][16];
    int lane = tid & 63, wid = tid >> 6;
    if (lane == 0) {
        shc[wid][0]=s0; shc[wid][1]=s1; shc[wid][2]=s2; shc[wid][3]=s3;
        shc[wid][4]=s4; shc[wid][5]=s5; shc[wid][6]=s6; shc[wid][7]=s7;
        shc[wid][8]=u0; shc[wid][9]=u1; shc[wid][10]=u2; shc[wid][11]=u3;
        shc[wid][12]=u4; shc[wid][13]=u5; shc[wid][14]=u6; shc[wid][15]=u7;
    }
    __syncthreads();
    if (tid < 16) {
        float tot = shc[0][tid] + shc[1][tid] + shc[2][tid] + shc[3][tid];
        int m = (tid < 8) ? m0 : m1;
        stat[(size_t)(tid & 7) * M_SLOTS + m] = tot;
    }
}

// both addressings, no max subtraction (cosine sim bounded by 1).  1 block x 1024.
__global__ __launch_bounds__(1024) void k_addr(
        const float* __restrict__ k, const float* __restrict__ kr, const float* __restrict__ a,
        const float* __restrict__ stat,
        float* __restrict__ ww, float* __restrict__ wr) {
    __shared__ float sh[17];
    int tid = threadIdx.x;
    float a0=0, a1=0, a2=0, a3=0;
    for (int i = tid; i < N_DIM; i += 1024) {
        float kv = k[i], krv = kr[i], av = a[i];
        a0 += kv*kv; a1 += krv*krv; a2 += av*krv; a3 += av*av;
    }
    float d0 = blk_sum_1024(a0, sh);
    float d1 = blk_sum_1024(a1, sh);
    float d2 = blk_sum_1024(a2, sh);
    float d3 = blk_sum_1024(a3, sh);
    float knorm = sqrtf(d0), krnorm = sqrtf(d1);

    const float* simk = stat + 0 * (size_t)M_SLOTS;
    const float* skr  = stat + 1 * (size_t)M_SLOTS;
    const float* sekr = stat + 2 * (size_t)M_SLOTS;
    const float* sa   = stat + 3 * (size_t)M_SLOTS;
    const float* sea  = stat + 4 * (size_t)M_SLOTS;
    const float* n2o  = stat + 5 * (size_t)M_SLOTS;
    const float* qe   = stat + 6 * (size_t)M_SLOTS;
    const float* qe2  = stat + 7 * (size_t)M_SLOTS;

    float ex[M_SLOTS / 1024];
    float n2l[M_SLOTS / 1024];
    float ls = 0.f;
    #pragma unroll
    for (int j = 0; j < M_SLOTS / 1024; ++j) {
        int m = tid + j * 1024;
        float n2 = n2o[m];
        n2l[j] = n2;
        float v = simk[m] / (sqrtf(n2) * knorm + EPS_F);
        ex[j] = expf(v);          // v in [-1,1]: no overflow, softmax identical
        ls += ex[j];
    }
    ls = blk_sum_1024(ls, sh);
    float inv = 1.f / ls;
    float wv[M_SLOTS / 1024];
    #pragma unroll
    for (int j = 0; j < M_SLOTS / 1024; ++j) {
        wv[j] = ex[j] * inv;
        ww[tid + j * 1024] = wv[j];
    }

    float ls2 = 0.f;
    #pragma unroll
    for (int j = 0; j < M_SLOTS / 1024; ++j) {
        int m = tid + j * 1024;
        float w1 = wv[j];
        float sim2 = skr[m] - w1 * sekr[m] + w1 * d2;
        float n2n  = n2l[j] - 2.f*w1*qe[m] + w1*w1*qe2[m]
                   + 2.f*w1*sa[m] - 2.f*w1*w1*sea[m] + w1*w1*d3;
        float v = sim2 / (sqrtf(n2n) * krnorm + EPS_F);
        ex[j] = expf(v);
        ls2 += ex[j];
    }
    ls2 = blk_sum_1024(ls2, sh);
    float inv2 = 1.f / ls2;
    #pragma unroll
    for (int j = 0; j < M_SLOTS / 1024; ++j) wr[tid + j * 1024] = ex[j] * inv2;
}

// mem_new = mem_old*(1-ww*e) + ww*a ; partial[rc] = sum wr*mem_new over 16 rows.
// grid (4, 512) x 256.  write_mem=0 on the last step (mem never read again).
__global__ void k_update_read(const float* __restrict__ src, float* __restrict__ dst,
                              const float* __restrict__ ww, const float* __restrict__ wr,
                              const float* __restrict__ e, const float* __restrict__ a,
                              float* __restrict__ partial, int write_mem) {
    int c4 = blockIdx.x * 256 + threadIdx.x;   // [0, 1024)
    int rc = blockIdx.y;                       // [0, 512)
    int r0 = rc * RCHUNK;
    const float4* s4 = (const float4*)src;
    float4*       d4 = (float4*)dst;
    float4 ee = ((const float4*)e)[c4];
    float4 aa = ((const float4*)a)[c4];
    float4 acc = make_float4(0.f, 0.f, 0.f, 0.f);
    if (write_mem) {
        #pragma unroll
        for (int r = r0; r < r0 + RCHUNK; ++r) {
            float w1 = ww[r], w2 = wr[r];
            float4 v = s4[(size_t)r * (N_DIM / 4) + c4];
            float4 nv;
            nv.x = v.x * (1.f - w1 * ee.x) + w1 * aa.x;
            nv.y = v.y * (1.f - w1 * ee.y) + w1 * aa.y;
            nv.z = v.z * (1.f - w1 * ee.z) + w1 * aa.z;
            nv.w = v.w * (1.f - w1 * ee.w) + w1 * aa.w;
            d4[(size_t)r * (N_DIM / 4) + c4] = nv;
            acc.x += w2 * nv.x; acc.y += w2 * nv.y; acc.z += w2 * nv.z; acc.w += w2 * nv.w;
        }
    } else {
        #pragma unroll
        for (int r = r0; r < r0 + RCHUNK; ++r) {
            float w1 = ww[r], w2 = wr[r];
            float4 v = s4[(size_t)r * (N_DIM / 4) + c4];
            float4 nv;
            nv.x = v.x * (1.f - w1 * ee.x) + w1 * aa.x;
            nv.y = v.y * (1.f - w1 * ee.y) + w1 * aa.y;
            nv.z = v.z * (1.f - w1 * ee.z) + w1 * aa.z;
            nv.w = v.w * (1.f - w1 * ee.w) + w1 * aa.w;
            acc.x += w2 * nv.x; acc.y += w2 * nv.y; acc.z += w2 * nv.z; acc.w += w2 * nv.w;
        }
    }
    ((float4*)partial)[(size_t)rc * (N_DIM / 4) + c4] = acc;
}

// red[c] = sum over 512 partial rows.  grid 64 x 256; block = 64 cols, 4 row-quarters.
__global__ void k_read_reduce(const float* __restrict__ partial, float* __restrict__ red) {
    __shared__ float gsh[4][64];
    int l = threadIdx.x & 63;
    int q = threadIdx.x >> 6;
    int c = blockIdx.x * 64 + l;
    float acc = 0.f;
    #pragma unroll 8
    for (int r = q * 128; r < q * 128 + 128; ++r)
        acc += partial[(size_t)r * N_DIM + c];
    gsh[q][l] = acc;
    __syncthreads();
    if (threadIdx.x < 64)
        red[blockIdx.x * 64 + threadIdx.x] =
            gsh[0][threadIdx.x] + gsh[1][threadIdx.x] + gsh[2][threadIdx.x] + gsh[3][threadIdx.x];
}

// X_new = tanh(X_old @ red.reshape(64,64)); c = sigmoid(Wc [X_new, prog_next] + bc)
// computed redundantly per block; waves then compute next step's keys.
// grid 512 x 256.  Only block 0 writes X_new to global.
__global__ __launch_bounds__(256) void k_exec_keys(
        const float* __restrict__ Xold, float* __restrict__ Xnew,
        const float* __restrict__ red, const float* __restrict__ prog_next,
        const float* __restrict__ Wc, const float* __restrict__ bc,
        const float* __restrict__ Wk, const float* __restrict__ bk,
        const float* __restrict__ We, const float* __restrict__ be,
        const float* __restrict__ Wa, const float* __restrict__ ba,
        const float* __restrict__ Wrk, const float* __restrict__ brk,
        float* __restrict__ k, float* __restrict__ e,
        float* __restrict__ a, float* __restrict__ kr) {
    __shared__ float xo[FVS];
    __shared__ float xs[FVS];
    __shared__ float cc[CDIM];
    int tid = threadIdx.x, lane = tid & 63, wid = tid >> 6;
    if (tid < FVS) xo[tid] = Xold[tid];
    __syncthreads();
    if (tid < FVS) {
        float acc = 0.f;
        #pragma unroll
        for (int i = 0; i < FVS; ++i) acc += xo[i] * red[i * FVS + tid];
        float xn = tanhf(acc);
        xs[tid] = xn;
        if (blockIdx.x == 0) Xnew[tid] = xn;
    }
    __syncthreads();
    {
        float acc = bc[tid];
        const float* wrow = Wc + tid * (FVS + PLEN);
        #pragma unroll
        for (int i = 0; i < FVS; ++i) acc += wrow[i] * xs[i];
        #pragma unroll
        for (int i = 0; i < PLEN; ++i) acc += wrow[FVS + i] * prog_next[i];
        cc[tid] = 1.f / (1.f + expf(-acc));
    }
    __syncthreads();
    const float4 cv = ((const float4*)cc)[lane];
    for (int gw = blockIdx.x * 4 + wid; gw < 4096; gw += 2048)
        keys_row(gw, cv, lane, prog_next, Wk, bk, We, be, Wa, ba, Wrk, brk, k, e, a, kr);
}

// final: X_new = tanh(X_old @ red); out = X_new @ out_emb.  1 block x 256.
__global__ void k_final(const float* __restrict__ Xold, const float* __restrict__ red,
                        const float* __restrict__ out_emb, float* __restrict__ out) {
    __shared__ float xo[FVS];
    __shared__ float xs[FVS];
    int tid = threadIdx.x;
    if (tid < FVS) xo[tid] = Xold[tid];
    __syncthreads();
    if (tid < FVS) {
        float acc = 0.f;
        #pragma unroll
        for (int i = 0; i < FVS; ++i) acc += xo[i] * red[i * FVS + tid];
        xs[tid] = tanhf(acc);
    }
    __syncthreads();
    for (int col = tid; col < NOUT; col += 256) {
        float acc = 0.f;
        #pragma unroll
        for (int i = 0; i < FVS; ++i) acc += xs[i] * out_emb[i * NOUT + col];
        out[col] = acc;
    }
}

// ---------------- launch ----------------

extern "C" void kernel_launch(void* const* d_in, const int* in_sizes, int n_in,
                              void* d_out, int out_size, void* d_ws, size_t ws_size,
                              hipStream_t stream) {
    const float* x        = (const float*)d_in[0];
    const float* program  = (const float*)d_in[1];
    const float* memory0  = (const float*)d_in[2];
    const float* in_emb   = (const float*)d_in[3];
    const float* out_emb  = (const float*)d_in[4];
    const float* Wc       = (const float*)d_in[5];
    const float* bc       = (const float*)d_in[6];
    const float* Wk       = (const float*)d_in[7];
    const float* bk       = (const float*)d_in[8];
    const float* We       = (const float*)d_in[9];
    const float* be       = (const float*)d_in[10];
    const float* Wa       = (const float*)d_in[11];
    const float* ba       = (const float*)d_in[12];
    const float* Wrk      = (const float*)d_in[13];
    const float* brk      = (const float*)d_in[14];
    float* out = (float*)d_out;

    float* ws = (float*)d_ws;
    size_t off = 0;
    float* mem     = ws + off; off += (size_t)M_SLOTS * N_DIM;
    float* partial = ws + off; off += (size_t)NCHUNKS * N_DIM;
    float* stat    = ws + off; off += (size_t)8 * M_SLOTS;
    float* Xb0     = ws + off; off += FVS;
    float* Xb1     = ws + off; off += FVS;
    float* c       = ws + off; off += CDIM;
    float* kv      = ws + off; off += N_DIM;
    float* ev      = ws + off; off += N_DIM;
    float* av      = ws + off; off += N_DIM;
    float* krv     = ws + off; off += N_DIM;
    float* ww      = ws + off; off += M_SLOTS;
    float* wr      = ws + off; off += M_SLOTS;
    float* red     = ws + off; off += N_DIM;

    k_init_ctrl<<<1, 256, 0, stream>>>(x, in_emb, program, Wc, bc, Xb0, c);
    k_keys4<<<512, 256, 0, stream>>>(c, program, Wk, bk, We, be, Wa, ba, Wrk, brk,
                                     kv, ev, av, krv);

    for (int t = 0; t < STEPS; ++t) {
        const float* src = (t == 0) ? memory0 : mem;

        k_sim8<<<4096, 256, 0, stream>>>(src, kv, krv, av, ev, stat);
        k_addr<<<1, 1024, 0, stream>>>(kv, krv, av, stat, ww, wr);
        k_update_read<<<dim3(4, NCHUNKS), 256, 0, stream>>>(
            src, mem, ww, wr, ev, av, partial, (t < STEPS - 1) ? 1 : 0);
        k_read_reduce<<<64, 256, 0, stream>>>(partial, red);

        const float* Xcur = (t & 1) ? Xb1 : Xb0;
        float*       Xnxt = (t & 1) ? Xb0 : Xb1;
        if (t < STEPS - 1) {
            k_exec_keys<<<512, 256, 0, stream>>>(
                Xcur, Xnxt, red, program + (t + 1) * PLEN,
                Wc, bc, Wk, bk, We, be, Wa, ba, Wrk, brk,
                kv, ev, av, krv);
        } else {
            k_final<<<1, 256, 0, stream>>>(Xcur, red, out_emb, out);
        }
    }
}